// Round 2
// baseline (325.343 us; speedup 1.0000x reference)
//
#include <hip/hip_runtime.h>

// out[b,i,c] = (1/(i+1)) * sum_{j<=i} x[b,j,c]   (running mean along T)
// All tensors fp32 per the reference. weights [8192,8192] is NEVER read:
// its row i is exactly fp32 1/(i+1) on the lower triangle (softmax of zeros),
// which we regenerate as 1.0f/(i+1).

#define BATCH 16
#define T 8192
#define C 64
#define CHUNK 128
#define NCH (T / CHUNK)   // 64 chunks per (batch)
#define ST (CHUNK / 16)   // 8 sequential t-steps per thread group row

// ---------- Pass 1: per-chunk per-channel sums  S[b, k, c] ----------
__global__ __launch_bounds__(256) void k_partial(const float* __restrict__ x,
                                                 float* __restrict__ S) {
    int blk = blockIdx.x;
    int b = blk >> 6;              // NCH = 64
    int k = blk & (NCH - 1);
    int tid = threadIdx.x;
    int cg = tid & 15;             // channel group: 4 channels (float4)
    int r  = tid >> 4;             // 16 t-subgroups of ST rows each
    int c0 = cg * 4;
    size_t base = (size_t)(b * T + k * CHUNK + r * ST) * C + c0;
    const float4* px = (const float4*)(x + base);
    float4 s = make_float4(0.f, 0.f, 0.f, 0.f);
#pragma unroll
    for (int i = 0; i < ST; ++i) {
        float4 v = px[i * (C / 4)];
        s.x += v.x; s.y += v.y; s.z += v.z; s.w += v.w;
    }
    __shared__ float lds[16][64];
    lds[r][c0 + 0] = s.x; lds[r][c0 + 1] = s.y;
    lds[r][c0 + 2] = s.z; lds[r][c0 + 3] = s.w;
    __syncthreads();
    if (tid < 64) {
        float sum = 0.f;
#pragma unroll
        for (int rr = 0; rr < 16; ++rr) sum += lds[rr][tid];
        S[(size_t)(b * NCH + k) * C + tid] = sum;
    }
}

// ---------- Pass 2: exclusive scan over chunks per (b,c) ----------
// 1024 (b,c) pairs = 4 blocks x 256 threads; each scans 64 chunk sums.
__global__ __launch_bounds__(256) void k_scan(const float* __restrict__ S,
                                              float* __restrict__ E) {
    int idx = blockIdx.x * 256 + threadIdx.x;   // (b,c)
    int b = idx >> 6;
    int c = idx & 63;
    float run = 0.f;
#pragma unroll 8
    for (int k = 0; k < NCH; ++k) {
        size_t i = (size_t)(b * NCH + k) * C + c;
        float v = S[i];
        E[i] = run;
        run += v;
    }
}

// ---------- Pass 3: local prefix + chunk base, scale by 1/(t+1) ----------
__global__ __launch_bounds__(256) void k_out(const float* __restrict__ x,
                                             const float* __restrict__ E,
                                             float* __restrict__ out) {
    int blk = blockIdx.x;
    int b = blk >> 6;
    int k = blk & (NCH - 1);
    int tid = threadIdx.x;
    int cg = tid & 15;
    int r  = tid >> 4;
    int c0 = cg * 4;
    int t0 = k * CHUNK + r * ST;
    size_t base = (size_t)(b * T + t0) * C + c0;
    const float4* px = (const float4*)(x + base);

    float4 vals[ST];
#pragma unroll
    for (int i = 0; i < ST; ++i) vals[i] = px[i * (C / 4)];

    float4 g = make_float4(0.f, 0.f, 0.f, 0.f);
#pragma unroll
    for (int i = 0; i < ST; ++i) {
        g.x += vals[i].x; g.y += vals[i].y; g.z += vals[i].z; g.w += vals[i].w;
    }
    __shared__ float lds[16][64];
    lds[r][c0 + 0] = g.x; lds[r][c0 + 1] = g.y;
    lds[r][c0 + 2] = g.z; lds[r][c0 + 3] = g.w;
    __syncthreads();

    // running base = chunk-exclusive prefix (E) + prefix of earlier r-groups
    const float4* eb = (const float4*)(E + (size_t)(b * NCH + k) * C + c0);
    float4 run = *eb;
    for (int rr = 0; rr < r; ++rr) {
        const float4* lrow = (const float4*)&lds[rr][c0];
        float4 p = *lrow;
        run.x += p.x; run.y += p.y; run.z += p.z; run.w += p.w;
    }

    float4* po = (float4*)(out + base);
#pragma unroll
    for (int i = 0; i < ST; ++i) {
        run.x += vals[i].x; run.y += vals[i].y;
        run.z += vals[i].z; run.w += vals[i].w;
        int t = t0 + i;
        float w = 1.0f / (float)(t + 1);   // == stored fp32 softmax weight
        float4 o;
        o.x = run.x * w; o.y = run.y * w;
        o.z = run.z * w; o.w = run.w * w;
        po[i * (C / 4)] = o;
    }
}

extern "C" void kernel_launch(void* const* d_in, const int* in_sizes, int n_in,
                              void* d_out, int out_size, void* d_ws, size_t ws_size,
                              hipStream_t stream) {
    // x is the input with BATCH*T*C elements (defensive against input order)
    const float* x = (const float*)d_in[0];
    if (n_in > 1 && in_sizes[0] != BATCH * T * C) x = (const float*)d_in[1];
    float* out = (float*)d_out;
    float* S = (float*)d_ws;                  // [16, 64, 64] chunk sums
    float* E = S + (size_t)BATCH * NCH * C;   // [16, 64, 64] exclusive prefixes

    k_partial<<<BATCH * NCH, 256, 0, stream>>>(x, S);
    k_scan<<<(BATCH * C) / 256, 256, 0, stream>>>(S, E);
    k_out<<<BATCH * NCH, 256, 0, stream>>>(x, E, out);
}

// Round 3
// 324.712 us; speedup vs baseline: 1.0019x; 1.0019x over previous
//
#include <hip/hip_runtime.h>

// out[b,i,c] = (1/(i+1)) * sum_{j<=i} x[b,j,c]   (running mean along T)
// All tensors fp32. weights [8192,8192] is NEVER read: its row i is exactly
// fp32 1/(i+1) on the lower triangle (softmax of zeros) -> regenerate as
// 1.0f/(i+1).
//
// Two passes:
//   A: per-chunk per-channel sums  S[b,k,c]   (16*64*64 fp32 = 256 KB in ws)
//   B: chunk base = sum_{k'<k} S[b,k',c] (L2-hot), + in-chunk prefix scan,
//      scale by 1/(t+1), store. Fused former pass-2 scan into B.

#define BATCH 16
#define T 8192
#define C 64
#define CHUNK 128
#define NCH (T / CHUNK)   // 64 chunks
#define ST (CHUNK / 16)   // 8 t-steps per (r) subgroup

// ---------- Pass A: per-chunk per-channel sums ----------
__global__ __launch_bounds__(256) void k_sum(const float* __restrict__ x,
                                             float* __restrict__ S) {
    int blk = blockIdx.x;
    int b = blk >> 6;
    int k = blk & (NCH - 1);
    int tid = threadIdx.x;
    int cg = tid & 15;             // 16 channel groups x float4
    int r  = tid >> 4;             // 16 t-subgroups
    int c0 = cg * 4;
    size_t base = (size_t)(b * T + k * CHUNK + r * ST) * C + c0;
    const float4* px = (const float4*)(x + base);
    float4 s = make_float4(0.f, 0.f, 0.f, 0.f);
#pragma unroll
    for (int i = 0; i < ST; ++i) {
        float4 v = px[i * (C / 4)];
        s.x += v.x; s.y += v.y; s.z += v.z; s.w += v.w;
    }
    __shared__ float lds[16][64];
    lds[r][c0 + 0] = s.x; lds[r][c0 + 1] = s.y;
    lds[r][c0 + 2] = s.z; lds[r][c0 + 3] = s.w;
    __syncthreads();
    if (tid < 64) {
        float sum = 0.f;
#pragma unroll
        for (int rr = 0; rr < 16; ++rr) sum += lds[rr][tid];
        S[(size_t)(b * NCH + k) * C + tid] = sum;
    }
}

// ---------- Pass B: base from S + local scan + scale + store ----------
__global__ __launch_bounds__(256) void k_out(const float* __restrict__ x,
                                             const float* __restrict__ S,
                                             float* __restrict__ out) {
    int blk = blockIdx.x;
    int b = blk >> 6;
    int k = blk & (NCH - 1);
    int tid = threadIdx.x;
    int cg = tid & 15;
    int r  = tid >> 4;
    int c0 = cg * 4;
    int t0 = k * CHUNK + r * ST;
    size_t base = (size_t)(b * T + t0) * C + c0;
    const float4* px = (const float4*)(x + base);

    // Issue HBM x-loads first so they overlap the L2-hot S reads below.
    float4 vals[ST];
#pragma unroll
    for (int i = 0; i < ST; ++i) vals[i] = px[i * (C / 4)];

    // Chunk base: sum_{k'<k} S[b,k',c].  Layout: 4 k-lanes x 64 channels.
    int cq = tid & 63;
    int kq = tid >> 6;
    float part = 0.f;
    for (int kk = kq; kk < k; kk += 4)
        part += S[(size_t)(b * NCH + kk) * C + cq];

    __shared__ float red[4][64];
    __shared__ float basev[64];
    __shared__ float lds[16][64];
    red[kq][cq] = part;
    __syncthreads();
    if (tid < 64)
        basev[tid] = red[0][tid] + red[1][tid] + red[2][tid] + red[3][tid];

    // In-chunk subgroup sums.
    float4 g = make_float4(0.f, 0.f, 0.f, 0.f);
#pragma unroll
    for (int i = 0; i < ST; ++i) {
        g.x += vals[i].x; g.y += vals[i].y; g.z += vals[i].z; g.w += vals[i].w;
    }
    lds[r][c0 + 0] = g.x; lds[r][c0 + 1] = g.y;
    lds[r][c0 + 2] = g.z; lds[r][c0 + 3] = g.w;
    __syncthreads();

    float4 run;
    run.x = basev[c0 + 0]; run.y = basev[c0 + 1];
    run.z = basev[c0 + 2]; run.w = basev[c0 + 3];
    for (int rr = 0; rr < r; ++rr) {
        run.x += lds[rr][c0 + 0]; run.y += lds[rr][c0 + 1];
        run.z += lds[rr][c0 + 2]; run.w += lds[rr][c0 + 3];
    }

    float4* po = (float4*)(out + base);
#pragma unroll
    for (int i = 0; i < ST; ++i) {
        run.x += vals[i].x; run.y += vals[i].y;
        run.z += vals[i].z; run.w += vals[i].w;
        float w = 1.0f / (float)(t0 + i + 1);   // == stored fp32 softmax weight
        float4 o;
        o.x = run.x * w; o.y = run.y * w;
        o.z = run.z * w; o.w = run.w * w;
        po[i * (C / 4)] = o;
    }
}

extern "C" void kernel_launch(void* const* d_in, const int* in_sizes, int n_in,
                              void* d_out, int out_size, void* d_ws, size_t ws_size,
                              hipStream_t stream) {
    const float* x = (const float*)d_in[0];
    if (n_in > 1 && in_sizes[0] != BATCH * T * C) x = (const float*)d_in[1];
    float* out = (float*)d_out;
    float* S = (float*)d_ws;   // [16, 64, 64] chunk sums (256 KB)

    k_sum<<<BATCH * NCH, 256, 0, stream>>>(x, S);
    k_out<<<BATCH * NCH, 256, 0, stream>>>(x, S, out);
}